// Round 3
// baseline (28078.894 us; speedup 1.0000x reference)
//
#include <hip/hip_runtime.h>
#include <math.h>

#define BB  4
#define LL  2048
#define KK  48
#define HH  128
#define XD  384
#define FFD 512
#define VELEMS ((size_t)BB * LL * HH)   // h_V element count = edge-region offset

typedef unsigned short u16;
typedef unsigned int   u32;

__device__ __forceinline__ float bf2f(u16 u) {
    return __uint_as_float(((u32)u) << 16);
}
__device__ __forceinline__ u16 f2bf(float f) {
    u32 u = __float_as_uint(f);
    return (u16)((u + 0x7fffu + ((u >> 16) & 1u)) >> 16);   // RNE
}
__device__ __forceinline__ float gelu(float x) {
    return 0.5f * x * (1.0f + erff(x * 0.70710678118654752f));
}

template<bool F32>
__device__ __forceinline__ float ld(const void* p, size_t i) {
    if constexpr (F32) return ((const float*)p)[i];
    else               return bf2f(((const u16*)p)[i]);
}
template<bool F32>
__device__ __forceinline__ void st(void* p, size_t i, float v) {
    if constexpr (F32) ((float*)p)[i] = v;
    else               ((u16*)p)[i] = f2bf(v);
}
template<bool F32>
__device__ __forceinline__ float dotrow(const void* w, size_t off, const float* x, int n) {
    float acc = 0.f;
    if constexpr (F32) {
        const float* p = (const float*)w + off;
        for (int i = 0; i < n; i += 4) {
            float4 q = *reinterpret_cast<const float4*>(p + i);
            acc += q.x*x[i] + q.y*x[i+1] + q.z*x[i+2] + q.w*x[i+3];
        }
    } else {
        const u16* p = (const u16*)w + off;
        for (int i = 0; i < n; i += 8) {
            uint4 q = *reinterpret_cast<const uint4*>(p + i);
            float f0 = __uint_as_float(q.x << 16), f1 = __uint_as_float(q.x & 0xffff0000u);
            float f2 = __uint_as_float(q.y << 16), f3 = __uint_as_float(q.y & 0xffff0000u);
            float f4 = __uint_as_float(q.z << 16), f5 = __uint_as_float(q.z & 0xffff0000u);
            float f6 = __uint_as_float(q.w << 16), f7 = __uint_as_float(q.w & 0xffff0000u);
            acc += f0*x[i]   + f1*x[i+1] + f2*x[i+2] + f3*x[i+3]
                 + f4*x[i+4] + f5*x[i+5] + f6*x[i+6] + f7*x[i+7];
        }
    }
    return acc;
}

__device__ __forceinline__ float block_sum(float v, float* red, int tid) {
    red[tid] = v;
    __syncthreads();
    for (int s = 64; s > 0; s >>= 1) {
        if (tid < s) red[tid] += red[tid + s];
        __syncthreads();
    }
    float r = red[0];
    __syncthreads();
    return r;
}

template<bool F32>
__device__ void node_body(
    const void* hV, const void* hE, const int* Eidx,
    const void* maskV, const void* maskAtt,
    const void* W1, const void* b1, const void* W2, const void* b2,
    const void* W3, const void* b3,
    const void* Win, const void* bin, const void* Wout, const void* bout,
    const void* g1, const void* be1, const void* g2, const void* be2,
    void* outV, float* outVf,
    float* xin, float* ybuf, float* zbuf, float* red, float* ff)
{
    const int bl = blockIdx.x;
    const int b  = bl / LL;
    const int o  = threadIdx.x;

    const float xself = ld<F32>(hV, (size_t)bl * HH + o);
    xin[o] = xself;
    const float bias1 = ld<F32>(b1, o);
    const float bias2 = ld<F32>(b2, o);
    const float bias3 = ld<F32>(b3, o);

    float msum = 0.f;
    const int ebase = bl * KK;
    for (int k = 0; k < KK; ++k) {
        __syncthreads();
        const int nb = Eidx[ebase + k];
        xin[HH + o]   = ld<F32>(hE, (size_t)(ebase + k) * HH + o);
        xin[2*HH + o] = ld<F32>(hV, (size_t)(b * LL + nb) * HH + o);
        __syncthreads();
        float y = gelu(bias1 + dotrow<F32>(W1, (size_t)o * XD, xin, XD));
        ybuf[o] = y;
        __syncthreads();
        float z = gelu(bias2 + dotrow<F32>(W2, (size_t)o * HH, ybuf, HH));
        zbuf[o] = z;
        __syncthreads();
        float msg = bias3 + dotrow<F32>(W3, (size_t)o * HH, zbuf, HH);
        msum += ld<F32>(maskAtt, (size_t)ebase + k) * msg;
    }

    float t  = xself + msum * (1.0f / 30.0f);
    float s1 = block_sum(t, red, o);
    float m  = s1 * (1.0f / 128.0f);
    float d  = t - m;
    float s2 = block_sum(d * d, red, o);
    float inv = rsqrtf(s2 * (1.0f / 128.0f) + 1e-5f);
    float hv1 = d * inv * ld<F32>(g1, o) + ld<F32>(be1, o);
    xin[o] = hv1;
    __syncthreads();

    for (int j = 0; j < 4; ++j) {
        int r = o + j * HH;
        ff[r] = gelu(ld<F32>(bin, r) + dotrow<F32>(Win, (size_t)r * HH, xin, HH));
    }
    __syncthreads();
    float dh2 = ld<F32>(bout, o) + dotrow<F32>(Wout, (size_t)o * FFD, ff, FFD);
    float t2  = hv1 + dh2;
    float u1  = block_sum(t2, red, o);
    float m2  = u1 * (1.0f / 128.0f);
    float d2  = t2 - m2;
    float u2  = block_sum(d2 * d2, red, o);
    float inv2 = rsqrtf(u2 * (1.0f / 128.0f) + 1e-5f);
    float hv2 = (d2 * inv2 * ld<F32>(g2, o) + ld<F32>(be2, o)) * ld<F32>(maskV, bl);
    st<F32>(outV, (size_t)bl * HH + o, hv2);
    if (outVf) outVf[(size_t)bl * HH + o] = hv2;
}

__global__ __launch_bounds__(128) void node_kernel(
    const void* hV, const void* hE, const int* Eidx,
    const void* maskV, const void* maskAtt,
    const void* W1, const void* b1, const void* W2, const void* b2,
    const void* W3, const void* b3,
    const void* Win, const void* bin, const void* Wout, const void* bout,
    const void* g1, const void* be1, const void* g2, const void* be2,
    void* outV, float* outVf)
{
    __shared__ float xin[XD];
    __shared__ float ybuf[HH];
    __shared__ float zbuf[HH];
    __shared__ float red[HH];
    __shared__ float ff[FFD];
    const bool isf32 = (*(const u32*)g1 == 0x3F800000u);   // ln1_g[0] == 1.0 probe
    if (isf32)
        node_body<true >(hV,hE,Eidx,maskV,maskAtt,W1,b1,W2,b2,W3,b3,Win,bin,Wout,bout,
                         g1,be1,g2,be2,outV,outVf,xin,ybuf,zbuf,red,ff);
    else
        node_body<false>(hV,hE,Eidx,maskV,maskAtt,W1,b1,W2,b2,W3,b3,Win,bin,Wout,bout,
                         g1,be1,g2,be2,outV,outVf,xin,ybuf,zbuf,red,ff);
}

template<bool F32>
__device__ void edge_body(
    const void* hE, const int* Eidx,
    const float* newVf, const void* dout,
    const void* W11, const void* b11, const void* W12, const void* b12,
    const void* W13, const void* b13,
    const void* g3, const void* be3,
    float* xin, float* ybuf, float* zbuf, float* red)
{
    const int e  = blockIdx.x;
    const int bl = e / KK;
    const int b  = bl / LL;
    const int o  = threadIdx.x;

    const int nb = Eidx[e];
    const float he = ld<F32>(hE, (size_t)e * HH + o);
    if (newVf) {
        xin[o]        = newVf[(size_t)bl * HH + o];
        xin[2*HH + o] = newVf[(size_t)(b * LL + nb) * HH + o];
    } else {
        xin[o]        = ld<F32>(dout, (size_t)bl * HH + o);
        xin[2*HH + o] = ld<F32>(dout, (size_t)(b * LL + nb) * HH + o);
    }
    xin[HH + o] = he;
    __syncthreads();
    float y = gelu(ld<F32>(b11, o) + dotrow<F32>(W11, (size_t)o * XD, xin, XD));
    ybuf[o] = y;
    __syncthreads();
    float z = gelu(ld<F32>(b12, o) + dotrow<F32>(W12, (size_t)o * HH, ybuf, HH));
    zbuf[o] = z;
    __syncthreads();
    float msg = ld<F32>(b13, o) + dotrow<F32>(W13, (size_t)o * HH, zbuf, HH);

    float t  = he + msg;
    float s1 = block_sum(t, red, o);
    float m  = s1 * (1.0f / 128.0f);
    float d  = t - m;
    float s2 = block_sum(d * d, red, o);
    float inv = rsqrtf(s2 * (1.0f / 128.0f) + 1e-5f);
    float outv = d * inv * ld<F32>(g3, o) + ld<F32>(be3, o);
    st<F32>((void*)dout, VELEMS + (size_t)e * HH + o, outv);   // edge region
}

__global__ __launch_bounds__(128) void edge_kernel(
    const void* hE, const int* Eidx,
    const float* newVf, void* dout,
    const void* W11, const void* b11, const void* W12, const void* b12,
    const void* W13, const void* b13,
    const void* g3, const void* be3, const void* g1probe)
{
    __shared__ float xin[XD];
    __shared__ float ybuf[HH];
    __shared__ float zbuf[HH];
    __shared__ float red[HH];
    const bool isf32 = (*(const u32*)g1probe == 0x3F800000u);
    if (isf32)
        edge_body<true >(hE,Eidx,newVf,dout,W11,b11,W12,b12,W13,b13,g3,be3,
                         xin,ybuf,zbuf,red);
    else
        edge_body<false>(hE,Eidx,newVf,dout,W11,b11,W12,b12,W13,b13,g3,be3,
                         xin,ybuf,zbuf,red);
}

extern "C" void kernel_launch(void* const* d_in, const int* in_sizes, int n_in,
                              void* d_out, int out_size, void* d_ws, size_t ws_size,
                              hipStream_t stream)
{
    const void* hV      = d_in[0];
    const void* hE      = d_in[1];
    const int*  Eidx    = (const int*)d_in[2];
    const void* maskV   = d_in[3];
    const void* maskAtt = d_in[4];
    const void* W1  = d_in[5];  const void* b1  = d_in[6];
    const void* W2  = d_in[7];  const void* b2  = d_in[8];
    const void* W3  = d_in[9];  const void* b3  = d_in[10];
    const void* W11 = d_in[11]; const void* b11 = d_in[12];
    const void* W12 = d_in[13]; const void* b12 = d_in[14];
    const void* W13 = d_in[15]; const void* b13 = d_in[16];
    const void* Win = d_in[17]; const void* bin = d_in[18];
    const void* Wout= d_in[19]; const void* bout= d_in[20];
    const void* g1  = d_in[21]; const void* be1 = d_in[22];
    const void* g2  = d_in[23]; const void* be2 = d_in[24];
    const void* g3  = d_in[25]; const void* be3 = d_in[26];

    float* newVf = (ws_size >= VELEMS * sizeof(float)) ? (float*)d_ws : nullptr;

    node_kernel<<<BB * LL, HH, 0, stream>>>(
        hV, hE, Eidx, maskV, maskAtt,
        W1, b1, W2, b2, W3, b3,
        Win, bin, Wout, bout,
        g1, be1, g2, be2, d_out, newVf);

    edge_kernel<<<BB * LL * KK, HH, 0, stream>>>(
        hE, Eidx, newVf, d_out,
        W11, b11, W12, b12, W13, b13,
        g3, be3, g1);
}